// Round 1
// baseline (324.746 us; speedup 1.0000x reference)
//
#include <hip/hip_runtime.h>
#include <math.h>

// SAE hierarchical fused kernel, fp32-exact.
// Layout: block = 1024 threads = 16 waves; lane = local row (64 rows/block);
// wave = feature slice. x row lives in 64 VGPRs per lane; W row address is
// wave-uniform -> scalar loads; top-k via sigma-threshold candidate push into
// LDS with count-check retry, then exact u64-key selection (jax tie-break).

#define D64   64
#define HID1  4096
#define HID2  2048
#define K1    32
#define K2    16
#define ROWS  64
#define NWAVE 16
#define CAP   176

__device__ __forceinline__ unsigned long long wave_max_u64(unsigned long long m) {
#pragma unroll
    for (int off = 32; off > 0; off >>= 1) {
        unsigned lo = (unsigned)m, hi = (unsigned)(m >> 32);
        unsigned olo = __shfl_xor(lo, off, 64);
        unsigned ohi = __shfl_xor(hi, off, 64);
        unsigned long long o = ((unsigned long long)ohi << 32) | (unsigned long long)olo;
        if (o > m) m = o;
    }
    return m;
}

__device__ __forceinline__ float wave_sum_f32(float v) {
#pragma unroll
    for (int off = 32; off > 0; off >>= 1) v += __shfl_xor(v, off, 64);
    return v;
}

__global__ __launch_bounds__(1024) void sae_hier_fused(
    const float* __restrict__ x,
    const float* __restrict__ W1,  const float* __restrict__ b1,
    const float* __restrict__ Wd1, const float* __restrict__ bd1,
    const float* __restrict__ W2,  const float* __restrict__ b2,
    const float* __restrict__ Wd2, const float* __restrict__ bd2,
    float* __restrict__ out)
{
    __shared__ uint2 s_buf[ROWS * CAP];     // exact (valbits, j) candidates per row
    __shared__ float s_recon[ROWS * 68];    // recon0, padded stride 68 (bank spread)
    __shared__ float s_t2[ROWS];
    __shared__ float s_scale[ROWS];
    __shared__ int   s_cnt[ROWS];
    __shared__ int   s_act[ROWS];
    __shared__ int   s_anybad;

    const int tid  = threadIdx.x;
    const int lane = tid & 63;
    const int w    = tid >> 6;
    const int wu   = __builtin_amdgcn_readfirstlane(w);
    const int rowbase = blockIdx.x * ROWS;

    if (tid < ROWS) { s_cnt[tid] = 0; s_scale[tid] = 1.0f; s_act[tid] = 1; }
    __syncthreads();

    // ---- load x row (lane = local row), subtract b_dec; row sum-of-squares ----
    float4 xq[16];
    {
        const float4* xp = reinterpret_cast<const float4*>(x) + (size_t)(rowbase + lane) * 16;
        const float4* bp = reinterpret_cast<const float4*>(bd1);
#pragma unroll
        for (int kk = 0; kk < 16; ++kk) {
            float4 a = xp[kk]; float4 b = bp[kk];
            xq[kk] = make_float4(a.x - b.x, a.y - b.y, a.z - b.z, a.w - b.w);
        }
    }
    float ss;
    {
        float a0 = 0.f, a1 = 0.f, a2 = 0.f, a3 = 0.f;
#pragma unroll
        for (int kk = 0; kk < 16; ++kk) {
            float4 c = xq[kk];
            a0 = fmaf(c.x, c.x, a0); a1 = fmaf(c.y, c.y, a1);
            a2 = fmaf(c.z, c.z, a2); a3 = fmaf(c.w, c.w, a3);
        }
        ss = (a0 + a2) + (a1 + a3);
    }
    const float tb1 = 0.25f * sqrtf(ss);   // 2 * sigma, sigma = ||x - b_dec|| / 8

    // ================= level 0: threshold push (with retry) =================
    for (int attempt = 0; attempt < 8; ++attempt) {
        const bool  act = (s_act[lane] != 0);
        const float thr = tb1 * s_scale[lane];
        const int jbase = wu * (HID1 / NWAVE);
#pragma unroll 1
        for (int jj = 0; jj < HID1 / NWAVE; ++jj) {
            const int j = jbase + jj;                      // wave-uniform
            const float4* Wp = reinterpret_cast<const float4*>(W1) + (size_t)j * 16;
            float a0 = 0.f, a1 = 0.f, a2 = 0.f, a3 = 0.f;
#pragma unroll
            for (int kk = 0; kk < 16; ++kk) {
                float4 c = Wp[kk]; float4 xx = xq[kk];
                a0 = fmaf(c.x, xx.x, a0); a1 = fmaf(c.y, xx.y, a1);
                a2 = fmaf(c.z, xx.z, a2); a3 = fmaf(c.w, xx.w, a3);
            }
            float v = ((a0 + a2) + (a1 + a3)) + b1[j];
            v = fmaxf(v, 0.0f);
            if (act && v > thr) {
                int slot = atomicAdd(&s_cnt[lane], 1);
                if (slot < CAP) s_buf[lane * CAP + slot] = make_uint2(__float_as_uint(v), (unsigned)j);
            }
        }
        __syncthreads();
        if (tid == 0) s_anybad = 0;
        __syncthreads();
        if (tid < ROWS) {
            int c = s_cnt[tid];
            bool lo = (c < K1), hi = (c > CAP);
            bool bad = (lo || hi) && (attempt < 7);
            s_act[tid] = bad ? 1 : 0;
            if (bad) { s_scale[tid] *= (lo ? 0.6f : 1.4f); s_cnt[tid] = 0; atomicAdd(&s_anybad, 1); }
        }
        __syncthreads();
        if (s_anybad == 0) break;
    }

    // ================= level 0: exact select + fused decode =================
#pragma unroll 1
    for (int q = 0; q < ROWS / NWAVE; ++q) {
        const int r = wu * (ROWS / NWAVE) + q;
        int n = s_cnt[r]; if (n > CAP) n = CAP;
        unsigned long long k0 = 0ull, k1 = 0ull, k2 = 0ull;
        if (lane < n)       { uint2 p = s_buf[r * CAP + lane];       k0 = ((unsigned long long)p.x << 32) | (unsigned)(~p.y); }
        if (lane + 64 < n)  { uint2 p = s_buf[r * CAP + lane + 64];  k1 = ((unsigned long long)p.x << 32) | (unsigned)(~p.y); }
        if (lane + 128 < n) { uint2 p = s_buf[r * CAP + lane + 128]; k2 = ((unsigned long long)p.x << 32) | (unsigned)(~p.y); }
        if (k1 > k0) { unsigned long long t = k0; k0 = k1; k1 = t; }
        if (k2 > k1) { unsigned long long t = k1; k1 = k2; k2 = t; }
        if (k1 > k0) { unsigned long long t = k0; k0 = k1; k1 = t; }
        unsigned savhi = 0u, savlo = 0u;
#pragma unroll 1
        for (int t = 0; t < K1; ++t) {
            unsigned long long m = wave_max_u64(k0);
            if (m == 0ull) break;                               // uniform
            if (lane == t) { savhi = (unsigned)(m >> 32); savlo = (unsigned)m; }
            if (k0 == m) { k0 = k1; k1 = k2; k2 = 0ull; }
        }
        float rec = bd1[lane];
#pragma unroll 1
        for (int t = 0; t < K1; ++t) {
            unsigned mhi = __shfl(savhi, t, 64);
            unsigned mlo = __shfl(savlo, t, 64);
            unsigned idx = (mhi != 0u) ? ~mlo : 0u;             // val==0 -> harmless row 0
            rec = fmaf(__uint_as_float(mhi), Wd1[(size_t)idx * D64 + lane], rec);
        }
        float e = wave_sum_f32(rec * rec);
        if (lane == 0) s_t2[r] = 0.25f * sqrtf(e);              // 2 * sigma for level 1
        s_recon[r * 68 + lane] = rec;
    }
    __syncthreads();

    // ================= level 1 =================
    if (tid < ROWS) { s_cnt[tid] = 0; s_scale[tid] = 1.0f; s_act[tid] = 1; }
    __syncthreads();

    float4 yq[16];
    {
        const float4* rp = reinterpret_cast<const float4*>(&s_recon[lane * 68]);
#pragma unroll
        for (int kk = 0; kk < 16; ++kk) yq[kk] = rp[kk];
    }
    const float tb2 = s_t2[lane];

    for (int attempt = 0; attempt < 8; ++attempt) {
        const bool  act = (s_act[lane] != 0);
        const float thr = tb2 * s_scale[lane];
        const int jbase = wu * (HID2 / NWAVE);
#pragma unroll 1
        for (int jj = 0; jj < HID2 / NWAVE; ++jj) {
            const int j = jbase + jj;
            const float4* Wp = reinterpret_cast<const float4*>(W2) + (size_t)j * 16;
            float a0 = 0.f, a1 = 0.f, a2 = 0.f, a3 = 0.f;
#pragma unroll
            for (int kk = 0; kk < 16; ++kk) {
                float4 c = Wp[kk]; float4 xx = yq[kk];
                a0 = fmaf(c.x, xx.x, a0); a1 = fmaf(c.y, xx.y, a1);
                a2 = fmaf(c.z, xx.z, a2); a3 = fmaf(c.w, xx.w, a3);
            }
            float v = ((a0 + a2) + (a1 + a3)) + b2[j];
            v = fmaxf(v, 0.0f);
            if (act && v > thr) {
                int slot = atomicAdd(&s_cnt[lane], 1);
                if (slot < CAP) s_buf[lane * CAP + slot] = make_uint2(__float_as_uint(v), (unsigned)j);
            }
        }
        __syncthreads();
        if (tid == 0) s_anybad = 0;
        __syncthreads();
        if (tid < ROWS) {
            int c = s_cnt[tid];
            bool lo = (c < K2), hi = (c > CAP);
            bool bad = (lo || hi) && (attempt < 7);
            s_act[tid] = bad ? 1 : 0;
            if (bad) { s_scale[tid] *= (lo ? 0.6f : 1.4f); s_cnt[tid] = 0; atomicAdd(&s_anybad, 1); }
        }
        __syncthreads();
        if (s_anybad == 0) break;
    }

    // ============ level 1: select + decode, combine, store ============
#pragma unroll 1
    for (int q = 0; q < ROWS / NWAVE; ++q) {
        const int r = wu * (ROWS / NWAVE) + q;
        int n = s_cnt[r]; if (n > CAP) n = CAP;
        unsigned long long k0 = 0ull, k1 = 0ull, k2 = 0ull;
        if (lane < n)       { uint2 p = s_buf[r * CAP + lane];       k0 = ((unsigned long long)p.x << 32) | (unsigned)(~p.y); }
        if (lane + 64 < n)  { uint2 p = s_buf[r * CAP + lane + 64];  k1 = ((unsigned long long)p.x << 32) | (unsigned)(~p.y); }
        if (lane + 128 < n) { uint2 p = s_buf[r * CAP + lane + 128]; k2 = ((unsigned long long)p.x << 32) | (unsigned)(~p.y); }
        if (k1 > k0) { unsigned long long t = k0; k0 = k1; k1 = t; }
        if (k2 > k1) { unsigned long long t = k1; k1 = k2; k2 = t; }
        if (k1 > k0) { unsigned long long t = k0; k0 = k1; k1 = t; }
        unsigned savhi = 0u, savlo = 0u;
#pragma unroll 1
        for (int t = 0; t < K2; ++t) {
            unsigned long long m = wave_max_u64(k0);
            if (m == 0ull) break;
            if (lane == t) { savhi = (unsigned)(m >> 32); savlo = (unsigned)m; }
            if (k0 == m) { k0 = k1; k1 = k2; k2 = 0ull; }
        }
        float rec1 = bd2[lane];
#pragma unroll 1
        for (int t = 0; t < K2; ++t) {
            unsigned mhi = __shfl(savhi, t, 64);
            unsigned mlo = __shfl(savlo, t, 64);
            unsigned idx = (mhi != 0u) ? ~mlo : 0u;
            rec1 = fmaf(__uint_as_float(mhi), Wd2[(size_t)idx * D64 + lane], rec1);
        }
        float rec0 = s_recon[r * 68 + lane];
        out[(size_t)(rowbase + r) * D64 + lane] = (1.0f / 1.5f) * rec0 + (0.5f / 1.5f) * rec1;
    }
}

extern "C" void kernel_launch(void* const* d_in, const int* in_sizes, int n_in,
                              void* d_out, int out_size, void* d_ws, size_t ws_size,
                              hipStream_t stream) {
    (void)n_in; (void)out_size; (void)d_ws; (void)ws_size;
    const float* x   = (const float*)d_in[0];
    const float* W1  = (const float*)d_in[1];
    const float* b1  = (const float*)d_in[2];
    const float* Wd1 = (const float*)d_in[3];
    const float* bd1 = (const float*)d_in[4];
    const float* W2  = (const float*)d_in[5];
    const float* b2  = (const float*)d_in[6];
    const float* Wd2 = (const float*)d_in[7];
    const float* bd2 = (const float*)d_in[8];

    const int batch = in_sizes[0] / D64;     // 16384
    const int grid  = batch / ROWS;          // 256 blocks, 1 per CU

    sae_hier_fused<<<grid, 1024, 0, stream>>>(x, W1, b1, Wd1, bd1, W2, b2, Wd2, bd2,
                                              (float*)d_out);
}

// Round 2
// 324.428 us; speedup vs baseline: 1.0010x; 1.0010x over previous
//
#include <hip/hip_runtime.h>
#include <math.h>

// SAE hierarchical fused kernel, fp32-exact.
// Layout: block = 1024 threads = 16 waves; lane = local row (64 rows/block);
// wave = feature slice. x row lives in 64 named-VGPR floats per lane (NO array
// -> compiler cannot demote to scratch); W row address is wave-uniform ->
// scalar loads; top-k via sigma-threshold candidate push into LDS with
// count-check retry, then exact u64-key selection (jax tie-break).

#define D64   64
#define HID1  4096
#define HID2  2048
#define K1    32
#define K2    16
#define ROWS  64
#define NWAVE 16
#define CAP   176

#define FOR16(M) M(0) M(1) M(2) M(3) M(4) M(5) M(6) M(7) \
                 M(8) M(9) M(10) M(11) M(12) M(13) M(14) M(15)

__device__ __forceinline__ unsigned long long wave_max_u64(unsigned long long m) {
#pragma unroll
    for (int off = 32; off > 0; off >>= 1) {
        unsigned lo = (unsigned)m, hi = (unsigned)(m >> 32);
        unsigned olo = __shfl_xor(lo, off, 64);
        unsigned ohi = __shfl_xor(hi, off, 64);
        unsigned long long o = ((unsigned long long)ohi << 32) | (unsigned long long)olo;
        if (o > m) m = o;
    }
    return m;
}

__device__ __forceinline__ float wave_sum_f32(float v) {
#pragma unroll
    for (int off = 32; off > 0; off >>= 1) v += __shfl_xor(v, off, 64);
    return v;
}

__global__ __launch_bounds__(1024) void sae_hier_fused(
    const float* __restrict__ x,
    const float* __restrict__ W1,  const float* __restrict__ b1,
    const float* __restrict__ Wd1, const float* __restrict__ bd1,
    const float* __restrict__ W2,  const float* __restrict__ b2,
    const float* __restrict__ Wd2, const float* __restrict__ bd2,
    float* __restrict__ out)
{
    __shared__ uint2 s_buf[ROWS * CAP];     // exact (valbits, j) candidates per row
    __shared__ float s_recon[ROWS * 68];    // recon0, padded stride 68
    __shared__ float s_t2[ROWS];
    __shared__ float s_scale[ROWS];
    __shared__ int   s_cnt[ROWS];
    __shared__ int   s_act[ROWS];
    __shared__ int   s_anybad;

    const int tid  = threadIdx.x;
    const int lane = tid & 63;
    const int w    = tid >> 6;
    const int wu   = __builtin_amdgcn_readfirstlane(w);
    const int rowbase = blockIdx.x * ROWS;

    if (tid < ROWS) { s_cnt[tid] = 0; s_scale[tid] = 1.0f; s_act[tid] = 1; }
    __syncthreads();

    // ---- x row in 16 NAMED float4 regs (lane = local row), minus b_dec ----
#define DECLX(kk) float4 x##kk;
    FOR16(DECLX)
#undef DECLX
    {
        const float4* xp = reinterpret_cast<const float4*>(x) + (size_t)(rowbase + lane) * 16;
        const float4* bp = reinterpret_cast<const float4*>(bd1);
#define LOADX(kk) { float4 a = xp[kk]; float4 b = bp[kk]; \
                    x##kk = make_float4(a.x-b.x, a.y-b.y, a.z-b.z, a.w-b.w); }
        FOR16(LOADX)
#undef LOADX
    }
    float tb1;
    {
        float a0 = 0.f, a1 = 0.f, a2 = 0.f, a3 = 0.f;
#define SSX(kk) { a0 = fmaf(x##kk.x, x##kk.x, a0); a1 = fmaf(x##kk.y, x##kk.y, a1); \
                  a2 = fmaf(x##kk.z, x##kk.z, a2); a3 = fmaf(x##kk.w, x##kk.w, a3); }
        FOR16(SSX)
#undef SSX
        tb1 = 0.25f * sqrtf((a0 + a2) + (a1 + a3));   // 2*sigma, sigma = ||x-b_dec||/8
    }

    // ================= level 0: threshold push (with retry) =================
    for (int attempt = 0; attempt < 8; ++attempt) {
        const bool  act = (s_act[lane] != 0);
        const float thr = tb1 * s_scale[lane];
        const int jbase = wu * (HID1 / NWAVE);
#pragma unroll 1
        for (int jj = 0; jj < HID1 / NWAVE; ++jj) {
            const int j = jbase + jj;                      // wave-uniform
            const float4* Wp = reinterpret_cast<const float4*>(W1) + (size_t)j * 16;
            float a0 = 0.f, a1 = 0.f, a2 = 0.f, a3 = 0.f;
#define STEPX(kk) { float4 wv = Wp[kk]; \
                    a0 = fmaf(wv.x, x##kk.x, a0); a1 = fmaf(wv.y, x##kk.y, a1); \
                    a2 = fmaf(wv.z, x##kk.z, a2); a3 = fmaf(wv.w, x##kk.w, a3); }
            FOR16(STEPX)
#undef STEPX
            float v = ((a0 + a2) + (a1 + a3)) + b1[j];
            v = fmaxf(v, 0.0f);
            if (act && v > thr) {
                int slot = atomicAdd(&s_cnt[lane], 1);
                if (slot < CAP) s_buf[lane * CAP + slot] = make_uint2(__float_as_uint(v), (unsigned)j);
            }
        }
        __syncthreads();
        if (tid == 0) s_anybad = 0;
        __syncthreads();
        if (tid < ROWS) {
            int c = s_cnt[tid];
            bool lo = (c < K1), hi = (c > CAP);
            bool bad = (lo || hi) && (attempt < 7);
            s_act[tid] = bad ? 1 : 0;
            if (bad) { s_scale[tid] *= (lo ? 0.6f : 1.4f); s_cnt[tid] = 0; atomicAdd(&s_anybad, 1); }
        }
        __syncthreads();
        if (s_anybad == 0) break;
    }

    // ================= level 0: exact select + fused decode =================
#pragma unroll 1
    for (int q = 0; q < ROWS / NWAVE; ++q) {
        const int r = wu * (ROWS / NWAVE) + q;
        int n = s_cnt[r]; if (n > CAP) n = CAP;
        unsigned long long k0 = 0ull, k1 = 0ull, k2 = 0ull;
        if (lane < n)       { uint2 p = s_buf[r * CAP + lane];       k0 = ((unsigned long long)p.x << 32) | (unsigned)(~p.y); }
        if (lane + 64 < n)  { uint2 p = s_buf[r * CAP + lane + 64];  k1 = ((unsigned long long)p.x << 32) | (unsigned)(~p.y); }
        if (lane + 128 < n) { uint2 p = s_buf[r * CAP + lane + 128]; k2 = ((unsigned long long)p.x << 32) | (unsigned)(~p.y); }
        if (k1 > k0) { unsigned long long t = k0; k0 = k1; k1 = t; }
        if (k2 > k1) { unsigned long long t = k1; k1 = k2; k2 = t; }
        if (k1 > k0) { unsigned long long t = k0; k0 = k1; k1 = t; }
        unsigned savhi = 0u, savlo = 0u;
#pragma unroll 1
        for (int t = 0; t < K1; ++t) {
            unsigned long long m = wave_max_u64(k0);
            if (m == 0ull) break;
            if (lane == t) { savhi = (unsigned)(m >> 32); savlo = (unsigned)m; }
            if (k0 == m) { k0 = k1; k1 = k2; k2 = 0ull; }
        }
        float rec = bd1[lane];
#pragma unroll 1
        for (int t = 0; t < K1; ++t) {
            unsigned mhi = __shfl(savhi, t, 64);
            unsigned mlo = __shfl(savlo, t, 64);
            unsigned idx = (mhi != 0u) ? ~mlo : 0u;
            rec = fmaf(__uint_as_float(mhi), Wd1[(size_t)idx * D64 + lane], rec);
        }
        float e = wave_sum_f32(rec * rec);
        if (lane == 0) s_t2[r] = 0.25f * sqrtf(e);              // 2*sigma for level 1
        s_recon[r * 68 + lane] = rec;
    }
    __syncthreads();

    // ================= level 1 =================
    if (tid < ROWS) { s_cnt[tid] = 0; s_scale[tid] = 1.0f; s_act[tid] = 1; }
    __syncthreads();

#define DECLY(kk) float4 y##kk;
    FOR16(DECLY)
#undef DECLY
    {
        const float4* rp = reinterpret_cast<const float4*>(&s_recon[lane * 68]);
#define LOADY(kk) y##kk = rp[kk];
        FOR16(LOADY)
#undef LOADY
    }
    const float tb2 = s_t2[lane];

    for (int attempt = 0; attempt < 8; ++attempt) {
        const bool  act = (s_act[lane] != 0);
        const float thr = tb2 * s_scale[lane];
        const int jbase = wu * (HID2 / NWAVE);
#pragma unroll 1
        for (int jj = 0; jj < HID2 / NWAVE; ++jj) {
            const int j = jbase + jj;
            const float4* Wp = reinterpret_cast<const float4*>(W2) + (size_t)j * 16;
            float a0 = 0.f, a1 = 0.f, a2 = 0.f, a3 = 0.f;
#define STEPY(kk) { float4 wv = Wp[kk]; \
                    a0 = fmaf(wv.x, y##kk.x, a0); a1 = fmaf(wv.y, y##kk.y, a1); \
                    a2 = fmaf(wv.z, y##kk.z, a2); a3 = fmaf(wv.w, y##kk.w, a3); }
            FOR16(STEPY)
#undef STEPY
            float v = ((a0 + a2) + (a1 + a3)) + b2[j];
            v = fmaxf(v, 0.0f);
            if (act && v > thr) {
                int slot = atomicAdd(&s_cnt[lane], 1);
                if (slot < CAP) s_buf[lane * CAP + slot] = make_uint2(__float_as_uint(v), (unsigned)j);
            }
        }
        __syncthreads();
        if (tid == 0) s_anybad = 0;
        __syncthreads();
        if (tid < ROWS) {
            int c = s_cnt[tid];
            bool lo = (c < K2), hi = (c > CAP);
            bool bad = (lo || hi) && (attempt < 7);
            s_act[tid] = bad ? 1 : 0;
            if (bad) { s_scale[tid] *= (lo ? 0.6f : 1.4f); s_cnt[tid] = 0; atomicAdd(&s_anybad, 1); }
        }
        __syncthreads();
        if (s_anybad == 0) break;
    }

    // ============ level 1: select + decode, combine, store ============
#pragma unroll 1
    for (int q = 0; q < ROWS / NWAVE; ++q) {
        const int r = wu * (ROWS / NWAVE) + q;
        int n = s_cnt[r]; if (n > CAP) n = CAP;
        unsigned long long k0 = 0ull, k1 = 0ull, k2 = 0ull;
        if (lane < n)       { uint2 p = s_buf[r * CAP + lane];       k0 = ((unsigned long long)p.x << 32) | (unsigned)(~p.y); }
        if (lane + 64 < n)  { uint2 p = s_buf[r * CAP + lane + 64];  k1 = ((unsigned long long)p.x << 32) | (unsigned)(~p.y); }
        if (lane + 128 < n) { uint2 p = s_buf[r * CAP + lane + 128]; k2 = ((unsigned long long)p.x << 32) | (unsigned)(~p.y); }
        if (k1 > k0) { unsigned long long t = k0; k0 = k1; k1 = t; }
        if (k2 > k1) { unsigned long long t = k1; k1 = k2; k2 = t; }
        if (k1 > k0) { unsigned long long t = k0; k0 = k1; k1 = t; }
        unsigned savhi = 0u, savlo = 0u;
#pragma unroll 1
        for (int t = 0; t < K2; ++t) {
            unsigned long long m = wave_max_u64(k0);
            if (m == 0ull) break;
            if (lane == t) { savhi = (unsigned)(m >> 32); savlo = (unsigned)m; }
            if (k0 == m) { k0 = k1; k1 = k2; k2 = 0ull; }
        }
        float rec1 = bd2[lane];
#pragma unroll 1
        for (int t = 0; t < K2; ++t) {
            unsigned mhi = __shfl(savhi, t, 64);
            unsigned mlo = __shfl(savlo, t, 64);
            unsigned idx = (mhi != 0u) ? ~mlo : 0u;
            rec1 = fmaf(__uint_as_float(mhi), Wd2[(size_t)idx * D64 + lane], rec1);
        }
        float rec0 = s_recon[r * 68 + lane];
        out[(size_t)(rowbase + r) * D64 + lane] = (1.0f / 1.5f) * rec0 + (0.5f / 1.5f) * rec1;
    }
}

extern "C" void kernel_launch(void* const* d_in, const int* in_sizes, int n_in,
                              void* d_out, int out_size, void* d_ws, size_t ws_size,
                              hipStream_t stream) {
    (void)n_in; (void)out_size; (void)d_ws; (void)ws_size;
    const float* x   = (const float*)d_in[0];
    const float* W1  = (const float*)d_in[1];
    const float* b1  = (const float*)d_in[2];
    const float* Wd1 = (const float*)d_in[3];
    const float* bd1 = (const float*)d_in[4];
    const float* W2  = (const float*)d_in[5];
    const float* b2  = (const float*)d_in[6];
    const float* Wd2 = (const float*)d_in[7];
    const float* bd2 = (const float*)d_in[8];

    const int batch = in_sizes[0] / D64;     // 16384
    const int grid  = batch / ROWS;          // 256 blocks, 1 per CU

    sae_hier_fused<<<grid, 1024, 0, stream>>>(x, W1, b1, Wd1, bd1, W2, b2, Wd2, bd2,
                                              (float*)d_out);
}